// Round 5
// baseline (362.049 us; speedup 1.0000x reference)
//
#include <hip/hip_runtime.h>
#include <hip/hip_bf16.h>

#define B_ 2
#define S_ 4096
#define H_ 8
#define D_ 64
#define BQ 128     // q-rows per WG (4 q-waves x 32 rows; x2 key-waves = 8 waves)
#define BK 64

#define GLOBAL_AS __attribute__((address_space(1)))
#define LDS_AS    __attribute__((address_space(3)))

typedef short bf16x8 __attribute__((ext_vector_type(8)));
typedef short bf16x4 __attribute__((ext_vector_type(4)));
typedef float f32x4  __attribute__((ext_vector_type(4)));
typedef float f32x16 __attribute__((ext_vector_type(16)));
typedef unsigned int u32x4 __attribute__((ext_vector_type(4)));

// log2(e)/8: folded into Q so the exp path is a bare v_exp_f32
#define QSCALE 0.18033688011112043f

__device__ __forceinline__ short f2bf(float f) {
    __bf16 h = (__bf16)f;                 // RTNE
    return __builtin_bit_cast(short, h);
}

__device__ __forceinline__ bf16x8 pack8(float4 f0, float4 f1) {
    bf16x8 r;
    r[0]=f2bf(f0.x); r[1]=f2bf(f0.y); r[2]=f2bf(f0.z); r[3]=f2bf(f0.w);
    r[4]=f2bf(f1.x); r[5]=f2bf(f1.y); r[6]=f2bf(f1.z); r[7]=f2bf(f1.w);
    return r;
}

__device__ __forceinline__ bf16x8 pack8s(float4 f0, float4 f1, float s) {
    bf16x8 r;
    r[0]=f2bf(f0.x*s); r[1]=f2bf(f0.y*s); r[2]=f2bf(f0.z*s); r[3]=f2bf(f0.w*s);
    r[4]=f2bf(f1.x*s); r[5]=f2bf(f1.y*s); r[6]=f2bf(f1.z*s); r[7]=f2bf(f1.w*s);
    return r;
}

// packed bf16 pair (lo=a, hi=b); compiler fuses to v_cvt_pk_bf16_f32
__device__ __forceinline__ unsigned pkbf(float a, float b) {
    unsigned ua = (unsigned)(unsigned short)__builtin_bit_cast(unsigned short, (__bf16)a);
    unsigned ub = (unsigned)(unsigned short)__builtin_bit_cast(unsigned short, (__bf16)b);
    return ua | (ub << 16);
}

// v_permlane32_swap_b32 a, b :  a' = [a.lo | b.lo], b' = [a.hi | b.hi]
// (HW-verified R6: swap(pk0,pk2) yields both PV-frag words directly)
__device__ __forceinline__ void perm32swap(unsigned &a, unsigned &b) {
    asm("v_permlane32_swap_b32 %0, %1" : "+v"(a), "+v"(b));
}

// ---- fused pre-pass: role 0 = K fp32 [B,S,H,D] -> bf16 [B,H,S,D]
//                      role 1 = V fp32 [B,S,H,D] -> bf16 transposed [B,H,D,S]
__global__ __launch_bounds__(256) void cast_kv_kernel(
    const float* __restrict__ kin, const float* __restrict__ vin,
    unsigned short* __restrict__ kb, unsigned short* __restrict__ vtb)
{
    __shared__ float Lf[64][72];
    const int role = blockIdx.z & 1;
    const int b    = blockIdx.z >> 1;
    const int h    = blockIdx.y;
    const int s0   = blockIdx.x * 64;
    const int t    = threadIdx.x;

    if (role == 0) {
        int r = t >> 2, fq = t & 3;
        const float4* gp = (const float4*)(kin + (((size_t)(b*S_ + s0 + r)*H_ + h)*D_ + fq*16));
        bf16x8 o0 = pack8(gp[0], gp[1]);
        bf16x8 o1 = pack8(gp[2], gp[3]);
        unsigned short* ob = kb + ((size_t)(b*H_ + h)*S_ + s0 + r)*D_ + fq*16;
        *(bf16x8*)ob       = o0;
        *(bf16x8*)(ob + 8) = o1;
    } else {
        {
            int r  = t >> 2, fq = t & 3;
            const float4* gp = (const float4*)(vin + (((size_t)(b*S_ + s0 + r)*H_ + h)*D_ + fq*16));
            #pragma unroll
            for (int j = 0; j < 4; ++j)
                *(f32x4*)&Lf[r][fq*16 + 4*j] = (f32x4){gp[j].x, gp[j].y, gp[j].z, gp[j].w};
        }
        __syncthreads();
        {
            int d = t >> 2, sq = t & 3;
            bf16x8 o0, o1;
            #pragma unroll
            for (int j = 0; j < 8; ++j) o0[j] = f2bf(Lf[sq*16 + j][d]);
            #pragma unroll
            for (int j = 0; j < 8; ++j) o1[j] = f2bf(Lf[sq*16 + 8 + j][d]);
            unsigned short* ob = vtb + (((size_t)(b*H_ + h)*D_ + d)*S_ + s0 + sq*16);
            *(bf16x8*)(ob)     = o0;
            *(bf16x8*)(ob + 8) = o1;
        }
    }
}

// ---------------- main flash-attention kernel ----------------
// R9: occupancy theory (R8) with the risk surface minimized. R8 failed
// correctness; its delta bundled {kw-split, 512-thr staging, raw-barrier
// dbuf pipeline}. R7 proved the pipeline is worth 0 (R6 drain 130us ==
// R7 pipelined 132us), so R9 drops it: single KV buffer + plain
// __syncthreads loop (R6 semantics, known-good). Keeps the occupancy fix:
// WG = 512 thr = 4 q-waves x 2 KEY-waves, each wave one 32q x 32k subtile;
// 1024 WGs x 8 waves -> 32 waves/CU = 8/SIMD (was 4/SIMD at ~130us,
// latency-bound: per-iter wall 9.9k cyc vs ~4.5k busiest-pipe work).
// LDS 16.9KB/WG (thread-limited 4 WG/CU, not LDS-limited). Runtime-indexed
// aoff[kw] replaced by register offsets koff/voff (rule #20). Key-wave
// partials combined at the end through the dead KV area in 2 dt-rounds.
// SPLIT: 2-way K-split, partial O^T + l to ws, combine kernel finishes.
template<bool SPLIT>
__global__ __launch_bounds__(512, 8) void fattn_kernel(
    const float* __restrict__ q, const unsigned short* __restrict__ kb,
    const unsigned short* __restrict__ vtb, float* __restrict__ out,
    float* __restrict__ Op, float* __restrict__ lw)
{
    __shared__ unsigned short KV[2][64][64];   // [0]=K keys x d, [1]=V^T d x keys
    __shared__ float lbuf[4][32];

    const int tid  = threadIdx.x;
    const int wave = tid >> 6;
    const int lane = tid & 63;
    const int l31  = tid & 31;
    const int hi   = lane >> 5;
    const int qw   = wave & 3;           // q-wave: which 32 q-rows
    const int kw   = wave >> 2;          // key-wave: which 32-key half
    const int h    = blockIdx.y;
    const int b    = SPLIT ? (blockIdx.z >> 1) : blockIdx.z;
    const int half = SPLIT ? (blockIdx.z & 1)  : 0;
    const int kt0  = half * 32;
    const int nkt  = SPLIT ? 32 : 64;
    const int q0   = blockIdx.x * BQ;
    const int bS   = b * S_;
    const int wq   = qw * 32;            // this wave's 32 q-rows

    // ---- per-lane LDS A-frag offsets (ushort units), kw folded in, swizzled:
    // K: row = kw*32 + l31 (key), logical d-chunk kc*2+hi, phys = ^ (row&7)
    // V: row = dt*32 + l31 (d), logical key-chunk (kw*2+c)*2+hi
    const int r7 = l31 & 7;
    int koff[4];
    #pragma unroll
    for (int kc = 0; kc < 4; ++kc)
        koff[kc] = (kw*32 + l31)*64 + (((kc*2 + hi) ^ r7)*8);
    int voff[2][2];
    #pragma unroll
    for (int dt = 0; dt < 2; ++dt)
        #pragma unroll
        for (int c = 0; c < 2; ++c)
            voff[dt][c] = (dt*32 + l31)*64 + ((((kw*2 + c)*2 + hi) ^ r7)*8);

    // ---- staging: 512 threads cover 64 rows x 8 chunks (16B each), 1 K + 1 V
    const int srow = tid >> 3;                  // 0..63, == wave*8 + (lane>>3)
    const int c8g  = (tid & 7) ^ (srow & 7);    // XOR pre-swizzled global chunk
    const unsigned short* ksg = kb  + ((size_t)(b*H_ + h)*S_ + srow)*64 + c8g*8;
    const unsigned short* vtg = vtb + ((size_t)(b*H_ + h)*D_ + srow)*(size_t)S_ + c8g*8;

    // ---- Q as B-frag of Q^T, pre-scaled: bq[kc], element j <-> d = kc*16+hi*8+j
    bf16x8 bq[4];
    {
        const int qrow = q0 + wq + l31;
        const float* qp = q + ((size_t)(bS + qrow)*H_ + h)*D_;
        #pragma unroll
        for (int kc = 0; kc < 4; ++kc) {
            const float4* q4 = (const float4*)(qp + kc*16 + hi*8);
            bq[kc] = pack8s(q4[0], q4[1], QSCALE);
        }
    }

    f32x16 oacc[2];
    #pragma unroll
    for (int dt = 0; dt < 2; ++dt)
        #pragma unroll
        for (int r = 0; r < 16; ++r) oacc[dt][r] = 0.f;
    float lp0 = 0.f, lp1 = 0.f;

    const unsigned short* Kb = &KV[0][0][0];
    const unsigned short* Vb = &KV[1][0][0];

    for (int i = 0; i < nkt; ++i) {
        const int kt = kt0 + i;
        __syncthreads();    // prev iteration done reading KV
        __builtin_amdgcn_global_load_lds(
            (const GLOBAL_AS void*)(ksg + (size_t)kt*BK*64),
            (LDS_AS void*)&KV[0][wave*8][0], 16, 0, 0);
        __builtin_amdgcn_global_load_lds(
            (const GLOBAL_AS void*)(vtg + (size_t)kt*BK),
            (LDS_AS void*)&KV[1][wave*8][0], 16, 0, 0);
        __syncthreads();    // vmcnt(0) drain + publish (R6 semantics)

        // ---- S^T subtile (32 keys [kw half] x 32 q) = K Q^T : 4 MFMAs, D=64
        f32x16 s;
        #pragma unroll
        for (int r = 0; r < 16; ++r) s[r] = 0.f;
        #pragma unroll
        for (int kc = 0; kc < 4; ++kc) {
            bf16x8 aK = *(const bf16x8*)&Kb[koff[kc]];
            s = __builtin_amdgcn_mfma_f32_32x32x16_bf16(aK, bq[kc], s, 0,0,0);
        }

        // ---- P = exp2(S^T); l-partials; pack bf16 pairs (rows 2r,2r+1)
        unsigned pk_[8];
        #pragma unroll
        for (int r = 0; r < 8; ++r) {
            float e0 = __builtin_exp2f(s[2*r]);
            float e1 = __builtin_exp2f(s[2*r+1]);
            lp0 += e0; lp1 += e1;
            pk_[r] = pkbf(e0, e1);
        }
        // ---- cross-half exchange -> PV B-frags (k = hi*8+j lane-local)
        perm32swap(pk_[0], pk_[2]);
        perm32swap(pk_[1], pk_[3]);
        perm32swap(pk_[4], pk_[6]);
        perm32swap(pk_[5], pk_[7]);
        u32x4 w0 = {pk_[0], pk_[1], pk_[2], pk_[3]};
        u32x4 w1 = {pk_[4], pk_[5], pk_[6], pk_[7]};
        bf16x8 bp0 = __builtin_bit_cast(bf16x8, w0);
        bf16x8 bp1 = __builtin_bit_cast(bf16x8, w1);

        // ---- O^T += V^T P^T (2 d-tiles x 2 key-chunks of this wave's half)
        #pragma unroll
        for (int dt = 0; dt < 2; ++dt) {
            bf16x8 aV0 = *(const bf16x8*)&Vb[voff[dt][0]];
            oacc[dt] = __builtin_amdgcn_mfma_f32_32x32x16_bf16(aV0, bp0, oacc[dt], 0,0,0);
            bf16x8 aV1 = *(const bf16x8*)&Vb[voff[dt][1]];
            oacc[dt] = __builtin_amdgcn_mfma_f32_32x32x16_bf16(aV1, bp1, oacc[dt], 0,0,0);
        }
    }

    // ---- per-wave l over its 32 keys (both hi halves)
    float lt0 = lp0 + lp1;
    float lt  = lt0 + __shfl_xor(lt0, 32);

    // ---- combine key-wave partials through the dead KV area, per dt round
    // (16KB = 4 waves x 64 lanes x 16 floats, exact fit)
    float* cb = (float*)&KV[0][0][0];
    #pragma unroll
    for (int dt = 0; dt < 2; ++dt) {
        __syncthreads();   // prior round's reads (or main loop) done
        if (wave >= 4) {
            float* base = cb + (wave - 4)*1024 + (hi*32 + l31)*16;
            #pragma unroll
            for (int rg = 0; rg < 4; ++rg)
                *(f32x4*)(base + rg*4) =
                    (f32x4){ oacc[dt][rg*4+0], oacc[dt][rg*4+1],
                             oacc[dt][rg*4+2], oacc[dt][rg*4+3] };
            if (dt == 0 && hi == 0) lbuf[wave - 4][l31] = lt;
        }
        __syncthreads();
        if (wave < 4) {
            const float* base = cb + qw*1024 + (hi*32 + l31)*16;
            #pragma unroll
            for (int rg = 0; rg < 4; ++rg) {
                f32x4 p = *(const f32x4*)(base + rg*4);
                oacc[dt][rg*4+0] += p[0]; oacc[dt][rg*4+1] += p[1];
                oacc[dt][rg*4+2] += p[2]; oacc[dt][rg*4+3] += p[3];
            }
        }
    }

    if (wave < 4) {
        lt += lbuf[qw][l31];
        const int orow = q0 + wq + l31;
        // oacc reg r of tile dt -> d = dt*32 + (r>>2)*8 + hi*4 + (r&3), col = q
        if constexpr (SPLIT) {
            float* ob = Op + (size_t)half*((size_t)B_*S_*H_*D_)
                           + ((size_t)(bS + orow)*H_ + h)*D_;
            #pragma unroll
            for (int dt = 0; dt < 2; ++dt)
                #pragma unroll
                for (int rg = 0; rg < 4; ++rg) {
                    float4 o4 = { oacc[dt][rg*4+0], oacc[dt][rg*4+1],
                                  oacc[dt][rg*4+2], oacc[dt][rg*4+3] };
                    *(float4*)(ob + dt*32 + rg*8 + hi*4) = o4;
                }
            if (hi == 0)
                lw[(size_t)half*((size_t)B_*S_*H_) + (size_t)(bS + orow)*H_ + h] = lt;
        } else {
            const float linv = 1.0f / lt;
            float* ob = out + ((size_t)(bS + orow)*H_ + h)*D_;
            #pragma unroll
            for (int dt = 0; dt < 2; ++dt)
                #pragma unroll
                for (int rg = 0; rg < 4; ++rg) {
                    float4 o4 = { oacc[dt][rg*4+0]*linv, oacc[dt][rg*4+1]*linv,
                                  oacc[dt][rg*4+2]*linv, oacc[dt][rg*4+3]*linv };
                    *(float4*)(ob + dt*32 + rg*8 + hi*4) = o4;
                }
        }
    }
}

// ---- combine: out = (O0 + O1) / (l0 + l1)
__global__ __launch_bounds__(256) void combine_kernel(
    const float* __restrict__ Op, const float* __restrict__ lw,
    float* __restrict__ out)
{
    const size_t NR = (size_t)B_*S_*H_;
    const size_t NO = NR * D_;
    const int t = threadIdx.x;
    size_t r  = (size_t)blockIdx.x * 16 + (t >> 4);
    int   c4  = t & 15;
    const float4* p0 = (const float4*)(Op + r*D_) + c4;
    const float4* p1 = (const float4*)(Op + NO + r*D_) + c4;
    float linv = 1.0f / (lw[r] + lw[NR + r]);
    float4 a = *p0, b = *p1;
    float4 o = { (a.x+b.x)*linv, (a.y+b.y)*linv, (a.z+b.z)*linv, (a.w+b.w)*linv };
    *((float4*)(out + r*D_) + c4) = o;
}

// ---------------- fallback (round-2 style, no workspace) ----------------
#define FBQ 64
#define LDK 72
__global__ __launch_bounds__(256, 4) void fattn_fb(
    const float* __restrict__ q, const float* __restrict__ k,
    const float* __restrict__ v, float* __restrict__ out)
{
    __shared__ unsigned short Ks [BK][LDK];
    __shared__ unsigned short Vts[D_][LDK];
    __shared__ unsigned short Ps [FBQ][LDK];
    const int tid  = threadIdx.x;
    const int wave = tid >> 6;
    const int m16  = tid & 15;
    const int quad = (tid & 63) >> 4;
    const int h    = blockIdx.y;
    const int b    = blockIdx.z;
    const int q0   = blockIdx.x * FBQ;
    const int bS   = b * S_;
    const int wq   = wave * 16;
    bf16x8 bq[2];
    {
        const int qrow = q0 + wq + m16;
        const float* qb = q + ((size_t)(bS + qrow)*H_ + h)*D_;
        #pragma unroll
        for (int kh = 0; kh < 2; ++kh) {
            const float4* qp = (const float4*)(qb + kh*32 + quad*8);
            bq[kh] = pack8s(qp[0], qp[1], QSCALE);
        }
    }
    const short ONE = 0x3F80;
    bf16x8 ones = { ONE,ONE,ONE,ONE,ONE,ONE,ONE,ONE };
    f32x4 oacc[4];
    f32x4 lacc = (f32x4){0.f,0.f,0.f,0.f};
    #pragma unroll
    for (int dt = 0; dt < 4; ++dt) oacc[dt] = (f32x4){0.f,0.f,0.f,0.f};
    const int vd  = tid & 63;
    const int vkg = tid >> 6;
    for (int kt = 0; kt < S_/BK; ++kt) {
        const int k0 = kt * BK;
        __syncthreads();
        #pragma unroll
        for (int i = 0; i < 2; ++i) {
            int chunk = tid + i*256;
            int row = chunk >> 3, c8 = chunk & 7;
            const float4* gp = (const float4*)(k + ((size_t)(bS + k0 + row)*H_ + h)*D_ + c8*8);
            *(bf16x8*)&Ks[row][c8*8] = pack8(gp[0], gp[1]);
        }
        {
            const float* vb = v + ((size_t)(bS + k0 + vkg*16)*H_ + h)*D_ + vd;
            bf16x8 t0, t1;
            #pragma unroll
            for (int i = 0; i < 8; ++i) t0[i] = f2bf(vb[(size_t)i * (H_*D_)]);
            #pragma unroll
            for (int i = 0; i < 8; ++i) t1[i] = f2bf(vb[(size_t)(i+8) * (H_*D_)]);
            *(bf16x8*)&Vts[vd][vkg*16]     = t0;
            *(bf16x8*)&Vts[vd][vkg*16 + 8] = t1;
        }
        __syncthreads();
        f32x4 sacc[4];
        #pragma unroll
        for (int mt = 0; mt < 4; ++mt) sacc[mt] = (f32x4){0.f,0.f,0.f,0.f};
        #pragma unroll
        for (int kh = 0; kh < 2; ++kh)
            #pragma unroll
            for (int mt = 0; mt < 4; ++mt) {
                bf16x8 aK = *(const bf16x8*)&Ks[mt*16 + m16][kh*32 + quad*8];
                sacc[mt] = __builtin_amdgcn_mfma_f32_16x16x32_bf16(aK, bq[kh], sacc[mt], 0,0,0);
            }
        #pragma unroll
        for (int mt = 0; mt < 4; ++mt) {
            bf16x4 pk;
            #pragma unroll
            for (int r = 0; r < 4; ++r)
                pk[r] = f2bf(__builtin_exp2f(sacc[mt][r]));
            *(bf16x4*)&Ps[wq + m16][mt*16 + quad*4] = pk;
        }
        #pragma unroll
        for (int kh = 0; kh < 2; ++kh) {
            bf16x8 bp = *(const bf16x8*)&Ps[wq + m16][kh*32 + quad*8];
            lacc = __builtin_amdgcn_mfma_f32_16x16x32_bf16(ones, bp, lacc, 0,0,0);
            #pragma unroll
            for (int dt = 0; dt < 4; ++dt) {
                bf16x8 aV = *(const bf16x8*)&Vts[dt*16 + m16][kh*32 + quad*8];
                oacc[dt] = __builtin_amdgcn_mfma_f32_16x16x32_bf16(aV, bp, oacc[dt], 0,0,0);
            }
        }
    }
    const float linv = 1.0f / lacc[0];
    const int orow = q0 + wq + m16;
    float* ob = out + ((size_t)(bS + orow)*H_ + h)*D_;
    #pragma unroll
    for (int dt = 0; dt < 4; ++dt) {
        float4 o4 = { oacc[dt][0]*linv, oacc[dt][1]*linv,
                      oacc[dt][2]*linv, oacc[dt][3]*linv };
        *(float4*)(ob + dt*16 + quad*4) = o4;
    }
}

extern "C" void kernel_launch(void* const* d_in, const int* in_sizes, int n_in,
                              void* d_out, int out_size, void* d_ws, size_t ws_size,
                              hipStream_t stream) {
    const float* q = (const float*)d_in[0];
    const float* k = (const float*)d_in[1];
    const float* v = (const float*)d_in[2];
    float* out = (float*)d_out;
    const size_t elems = (size_t)B_*H_*S_*D_;                 // 4.19M
    const size_t NR    = (size_t)B_*S_*H_;                    // 65536
    const size_t need_cast  = 2 * elems * sizeof(unsigned short);
    const size_t need_split = need_cast + 2*elems*sizeof(float) + 2*NR*sizeof(float);

    if (ws_size >= need_split) {
        unsigned short* kb  = (unsigned short*)d_ws;
        unsigned short* vtb = kb + elems;
        float* Op = (float*)(vtb + elems);
        float* lw = Op + 2*elems;
        cast_kv_kernel<<<dim3(S_/64, H_, B_*2), dim3(256), 0, stream>>>(k, v, kb, vtb);
        fattn_kernel<true><<<dim3(S_/BQ, H_, B_*2), dim3(512), 0, stream>>>(
            q, kb, vtb, out, Op, lw);
        combine_kernel<<<dim3((int)(NR/16)), dim3(256), 0, stream>>>(Op, lw, out);
    } else if (ws_size >= need_cast) {
        unsigned short* kb  = (unsigned short*)d_ws;
        unsigned short* vtb = kb + elems;
        cast_kv_kernel<<<dim3(S_/64, H_, B_*2), dim3(256), 0, stream>>>(k, v, kb, vtb);
        fattn_kernel<false><<<dim3(S_/BQ, H_, B_), dim3(512), 0, stream>>>(
            q, kb, vtb, out, nullptr, nullptr);
    } else {
        fattn_fb<<<dim3(S_/FBQ, H_, B_), dim3(256), 0, stream>>>(q, k, v, out);
    }
}

// Round 6
// 206.018 us; speedup vs baseline: 1.7574x; 1.7574x over previous
//
#include <hip/hip_runtime.h>
#include <hip/hip_bf16.h>

#define B_ 2
#define S_ 4096
#define H_ 8
#define D_ 64
#define BQ 128     // q-rows per WG (4 waves x 32 rows)
#define BK 128     // keys per iteration (R10: doubled to amortize per-iter fixed cost)

#define GLOBAL_AS __attribute__((address_space(1)))
#define LDS_AS    __attribute__((address_space(3)))

typedef short bf16x8 __attribute__((ext_vector_type(8)));
typedef short bf16x4 __attribute__((ext_vector_type(4)));
typedef float f32x4  __attribute__((ext_vector_type(4)));
typedef float f32x16 __attribute__((ext_vector_type(16)));
typedef unsigned int u32x4 __attribute__((ext_vector_type(4)));

// log2(e)/8: folded into Q so the exp path is a bare v_exp_f32
#define QSCALE 0.18033688011112043f

__device__ __forceinline__ short f2bf(float f) {
    __bf16 h = (__bf16)f;                 // RTNE
    return __builtin_bit_cast(short, h);
}

__device__ __forceinline__ bf16x8 pack8(float4 f0, float4 f1) {
    bf16x8 r;
    r[0]=f2bf(f0.x); r[1]=f2bf(f0.y); r[2]=f2bf(f0.z); r[3]=f2bf(f0.w);
    r[4]=f2bf(f1.x); r[5]=f2bf(f1.y); r[6]=f2bf(f1.z); r[7]=f2bf(f1.w);
    return r;
}

__device__ __forceinline__ bf16x8 pack8s(float4 f0, float4 f1, float s) {
    bf16x8 r;
    r[0]=f2bf(f0.x*s); r[1]=f2bf(f0.y*s); r[2]=f2bf(f0.z*s); r[3]=f2bf(f0.w*s);
    r[4]=f2bf(f1.x*s); r[5]=f2bf(f1.y*s); r[6]=f2bf(f1.z*s); r[7]=f2bf(f1.w*s);
    return r;
}

// packed bf16 pair (lo=a, hi=b); compiler fuses to v_cvt_pk_bf16_f32
__device__ __forceinline__ unsigned pkbf(float a, float b) {
    unsigned ua = (unsigned)(unsigned short)__builtin_bit_cast(unsigned short, (__bf16)a);
    unsigned ub = (unsigned)(unsigned short)__builtin_bit_cast(unsigned short, (__bf16)b);
    return ua | (ub << 16);
}

// v_permlane32_swap_b32 a, b :  a' = [a.lo | b.lo], b' = [a.hi | b.hi]
// (HW-verified R6: swap(pk0,pk2) yields both PV-frag words directly)
__device__ __forceinline__ void perm32swap(unsigned &a, unsigned &b) {
    asm("v_permlane32_swap_b32 %0, %1" : "+v"(a), "+v"(b));
}

// ---- fused pre-pass: role 0 = K fp32 [B,S,H,D] -> bf16 [B,H,S,D]
//                      role 1 = V fp32 [B,S,H,D] -> bf16 transposed [B,H,D,S]
__global__ __launch_bounds__(256) void cast_kv_kernel(
    const float* __restrict__ kin, const float* __restrict__ vin,
    unsigned short* __restrict__ kb, unsigned short* __restrict__ vtb)
{
    __shared__ float Lf[64][72];
    const int role = blockIdx.z & 1;
    const int b    = blockIdx.z >> 1;
    const int h    = blockIdx.y;
    const int s0   = blockIdx.x * 64;
    const int t    = threadIdx.x;

    if (role == 0) {
        int r = t >> 2, fq = t & 3;
        const float4* gp = (const float4*)(kin + (((size_t)(b*S_ + s0 + r)*H_ + h)*D_ + fq*16));
        bf16x8 o0 = pack8(gp[0], gp[1]);
        bf16x8 o1 = pack8(gp[2], gp[3]);
        unsigned short* ob = kb + ((size_t)(b*H_ + h)*S_ + s0 + r)*D_ + fq*16;
        *(bf16x8*)ob       = o0;
        *(bf16x8*)(ob + 8) = o1;
    } else {
        {
            int r  = t >> 2, fq = t & 3;
            const float4* gp = (const float4*)(vin + (((size_t)(b*S_ + s0 + r)*H_ + h)*D_ + fq*16));
            #pragma unroll
            for (int j = 0; j < 4; ++j)
                *(f32x4*)&Lf[r][fq*16 + 4*j] = (f32x4){gp[j].x, gp[j].y, gp[j].z, gp[j].w};
        }
        __syncthreads();
        {
            int d = t >> 2, sq = t & 3;
            bf16x8 o0, o1;
            #pragma unroll
            for (int j = 0; j < 8; ++j) o0[j] = f2bf(Lf[sq*16 + j][d]);
            #pragma unroll
            for (int j = 0; j < 8; ++j) o1[j] = f2bf(Lf[sq*16 + 8 + j][d]);
            unsigned short* ob = vtb + (((size_t)(b*H_ + h)*D_ + d)*S_ + s0 + sq*16);
            *(bf16x8*)(ob)     = o0;
            *(bf16x8*)(ob + 8) = o1;
        }
    }
}

// ---------------- main flash-attention kernel ----------------
// R10 = R6 (verified 130us base: 256 thr, 4 waves x 32q, drain loop,
// in-register P via cvt_pk + permlane32_swap) with BK doubled to 128.
// R9 taught: occupancy push thrashes L2 (fetch 75->835MB) because slab-
// sharing WGs must stay tile-synchronized; R6's binder is per-iteration
// fixed cost (wall 9.9k cyc/iter vs ~4.5k work). BK=128 halves iterations
// (16 w/ SPLIT), halves barriers/latency exposures, same totals elsewhere.
// LDS 32KB/WG (4 WG/CU unchanged), FETCH unchanged (line-exact patterns).
// K LDS [128][64] swizzled chunk^row&7; V^T LDS [64][128] swizzled
// keychunk^(d&7) — staging pre-applies the same involution per lane.
// SPLIT: 2-way K-split, partial O^T + l to ws, combine kernel finishes.
template<bool SPLIT>
__global__ __launch_bounds__(256, 4) void fattn_kernel(
    const float* __restrict__ q, const unsigned short* __restrict__ kb,
    const unsigned short* __restrict__ vtb, float* __restrict__ out,
    float* __restrict__ Op, float* __restrict__ lw)
{
    __shared__ unsigned short Ks [BK][64];    // 16KB: keys x d
    __shared__ unsigned short Vts[D_][BK];    // 16KB: d x keys

    const int tid  = threadIdx.x;
    const int wave = tid >> 6;
    const int lane = tid & 63;
    const int l31  = tid & 31;
    const int hi   = lane >> 5;
    const int h    = blockIdx.y;
    const int b    = SPLIT ? (blockIdx.z >> 1) : blockIdx.z;
    const int half = SPLIT ? (blockIdx.z & 1)  : 0;
    const int kt0  = half * 16;
    const int nkt  = SPLIT ? 16 : 32;
    const int q0   = blockIdx.x * BQ;
    const int bS   = b * S_;
    const int wq   = wave * 32;          // this wave's 32 q-rows

    // ---- read-side swizzle decomposition (r7 = LDS row & 7)
    const int r7 = l31 & 7;
    const int q2 = r7 >> 1;              // bits 1-2 of r7
    const int r2 = r7 >> 2;              // bit 2 of r7
    const int h0 = hi ^ (r7 & 1);        // bit 0 after XOR

    // K A-frag base (ushort idx into Ks flat): addr(mt,kc) = k0[kc] + mt*2048
    // derivation: chunk = (kc*2+hi)^r7 = ((kc^q2)*2 + h0)
    int k0[4];
    #pragma unroll
    for (int kc = 0; kc < 4; ++kc)
        k0[kc] = l31*64 + ((kc ^ q2)*2 + h0)*8;
    // V A-frag base: addr(dt,mt,c) = v0[c][mt&1] + (mt>>1)*64 + dt*4096
    // derivation: keychunk = (mt*4+c*2+hi)^r7
    //   = ((c*2+hi)^(r7&3)) + 4*((mt&1)^r2) + 8*(mt>>1)
    int v0[2][2];
    #pragma unroll
    for (int c = 0; c < 2; ++c)
        #pragma unroll
        for (int m1 = 0; m1 < 2; ++m1)
            v0[c][m1] = l31*128 + (((c*2 + hi) ^ (r7 & 3))*8) + ((m1 ^ r2)*32);

    // ---- staging lane mapping (pre-swizzled global source, linear LDS dest)
    // K: wave stages rows {it*32 + wave*8 + (lane>>3)}, phys chunk lane&7,
    //    logical chunk = (lane&7) ^ (lane>>3)   [row&7 == lane>>3]
    const unsigned short* ksg =
        kb + ((size_t)(b*H_ + h)*S_ + wave*8 + (lane>>3))*64 + ((lane&7) ^ (lane>>3))*8;
    // V^T: wave stages d-rows {wave*16 + it*4 + (lane>>4)}, phys chunk lane&15,
    //    logical = (lane&15) ^ ((it*4 + (lane>>4)) & 7); it even/odd differ by ^4
    const int vce = (lane & 15) ^ (lane >> 4);
    const unsigned short* vt0 =
        vtb + ((size_t)(b*H_ + h)*D_ + wave*16 + 0 + (lane>>4))*(size_t)S_ + vce*8;
    const unsigned short* vt1 =
        vtb + ((size_t)(b*H_ + h)*D_ + wave*16 + 4 + (lane>>4))*(size_t)S_ + (vce ^ 4)*8;

    // ---- Q as B-frag of Q^T, pre-scaled: bq[kc], element j <-> d = kc*16+hi*8+j
    bf16x8 bq[4];
    {
        const int qrow = q0 + wq + l31;
        const float* qp = q + ((size_t)(bS + qrow)*H_ + h)*D_;
        #pragma unroll
        for (int kc = 0; kc < 4; ++kc) {
            const float4* q4 = (const float4*)(qp + kc*16 + hi*8);
            bq[kc] = pack8s(q4[0], q4[1], QSCALE);
        }
    }

    f32x16 oacc[2];
    #pragma unroll
    for (int dt = 0; dt < 2; ++dt)
        #pragma unroll
        for (int r = 0; r < 16; ++r) oacc[dt][r] = 0.f;
    float lp0 = 0.f, lp1 = 0.f;

    const unsigned short* Kf = &Ks[0][0];
    const unsigned short* Vf = &Vts[0][0];

    for (int i = 0; i < nkt; ++i) {
        const int kt = kt0 + i;
        __syncthreads();    // prev iteration done reading LDS
        {
            const unsigned short* kp = ksg + (size_t)kt*BK*64;
            #pragma unroll
            for (int it = 0; it < 4; ++it)
                __builtin_amdgcn_global_load_lds(
                    (const GLOBAL_AS void*)(kp + it*32*64),
                    (LDS_AS void*)&Ks[it*32 + wave*8][0], 16, 0, 0);
            const unsigned short* vp0 = vt0 + (size_t)kt*BK;
            const unsigned short* vp1 = vt1 + (size_t)kt*BK;
            __builtin_amdgcn_global_load_lds(
                (const GLOBAL_AS void*)(vp0),            (LDS_AS void*)&Vts[wave*16 +  0][0], 16, 0, 0);
            __builtin_amdgcn_global_load_lds(
                (const GLOBAL_AS void*)(vp1),            (LDS_AS void*)&Vts[wave*16 +  4][0], 16, 0, 0);
            __builtin_amdgcn_global_load_lds(
                (const GLOBAL_AS void*)(vp0 + 8*(size_t)S_), (LDS_AS void*)&Vts[wave*16 +  8][0], 16, 0, 0);
            __builtin_amdgcn_global_load_lds(
                (const GLOBAL_AS void*)(vp1 + 8*(size_t)S_), (LDS_AS void*)&Vts[wave*16 + 12][0], 16, 0, 0);
        }
        __syncthreads();    // vmcnt(0) drain + publish (R6 semantics)

        #pragma unroll
        for (int mt = 0; mt < 4; ++mt) {
            // ---- S^T subtile (32 keys x 32 q) = K Q^T : 4 MFMAs over D=64
            f32x16 s;
            #pragma unroll
            for (int r = 0; r < 16; ++r) s[r] = 0.f;
            #pragma unroll
            for (int kc = 0; kc < 4; ++kc) {
                bf16x8 aK = *(const bf16x8*)&Kf[k0[kc] + mt*2048];
                s = __builtin_amdgcn_mfma_f32_32x32x16_bf16(aK, bq[kc], s, 0,0,0);
            }

            // ---- P = exp2(S^T); l-partials; pack bf16 pairs (rows 2r,2r+1)
            unsigned pk_[8];
            #pragma unroll
            for (int r = 0; r < 8; ++r) {
                float e0 = __builtin_exp2f(s[2*r]);
                float e1 = __builtin_exp2f(s[2*r+1]);
                lp0 += e0; lp1 += e1;
                pk_[r] = pkbf(e0, e1);
            }
            // ---- cross-half exchange -> PV B-frags (k = hi*8+j lane-local)
            perm32swap(pk_[0], pk_[2]);
            perm32swap(pk_[1], pk_[3]);
            perm32swap(pk_[4], pk_[6]);
            perm32swap(pk_[5], pk_[7]);
            u32x4 w0 = {pk_[0], pk_[1], pk_[2], pk_[3]};
            u32x4 w1 = {pk_[4], pk_[5], pk_[6], pk_[7]};
            bf16x8 bp0 = __builtin_bit_cast(bf16x8, w0);
            bf16x8 bp1 = __builtin_bit_cast(bf16x8, w1);

            // ---- O^T += V^T P^T (2 d-tiles x 2 key-chunks of this m-tile)
            #pragma unroll
            for (int dt = 0; dt < 2; ++dt) {
                bf16x8 aV0 = *(const bf16x8*)&Vf[v0[0][mt & 1] + (mt >> 1)*64 + dt*4096];
                oacc[dt] = __builtin_amdgcn_mfma_f32_32x32x16_bf16(aV0, bp0, oacc[dt], 0,0,0);
                bf16x8 aV1 = *(const bf16x8*)&Vf[v0[1][mt & 1] + (mt >> 1)*64 + dt*4096];
                oacc[dt] = __builtin_amdgcn_mfma_f32_32x32x16_bf16(aV1, bp1, oacc[dt], 0,0,0);
            }
        }
    }

    // ---- epilogue: l = own-half partial + partner-half partial
    float lt0 = lp0 + lp1;
    float lt  = lt0 + __shfl_xor(lt0, 32);
    const int orow = q0 + wq + l31;
    // oacc reg r of tile dt -> d = dt*32 + (r>>2)*8 + hi*4 + (r&3), col = q
    if constexpr (SPLIT) {
        float* ob = Op + (size_t)half*((size_t)B_*S_*H_*D_)
                       + ((size_t)(bS + orow)*H_ + h)*D_;
        #pragma unroll
        for (int dt = 0; dt < 2; ++dt)
            #pragma unroll
            for (int rg = 0; rg < 4; ++rg) {
                float4 o4 = { oacc[dt][rg*4+0], oacc[dt][rg*4+1],
                              oacc[dt][rg*4+2], oacc[dt][rg*4+3] };
                *(float4*)(ob + dt*32 + rg*8 + hi*4) = o4;
            }
        if (hi == 0)
            lw[(size_t)half*((size_t)B_*S_*H_) + (size_t)(bS + orow)*H_ + h] = lt;
    } else {
        const float linv = 1.0f / lt;
        float* ob = out + ((size_t)(bS + orow)*H_ + h)*D_;
        #pragma unroll
        for (int dt = 0; dt < 2; ++dt)
            #pragma unroll
            for (int rg = 0; rg < 4; ++rg) {
                float4 o4 = { oacc[dt][rg*4+0]*linv, oacc[dt][rg*4+1]*linv,
                              oacc[dt][rg*4+2]*linv, oacc[dt][rg*4+3]*linv };
                *(float4*)(ob + dt*32 + rg*8 + hi*4) = o4;
            }
    }
}

// ---- combine: out = (O0 + O1) / (l0 + l1)
__global__ __launch_bounds__(256) void combine_kernel(
    const float* __restrict__ Op, const float* __restrict__ lw,
    float* __restrict__ out)
{
    const size_t NR = (size_t)B_*S_*H_;
    const size_t NO = NR * D_;
    const int t = threadIdx.x;
    size_t r  = (size_t)blockIdx.x * 16 + (t >> 4);
    int   c4  = t & 15;
    const float4* p0 = (const float4*)(Op + r*D_) + c4;
    const float4* p1 = (const float4*)(Op + NO + r*D_) + c4;
    float linv = 1.0f / (lw[r] + lw[NR + r]);
    float4 a = *p0, b = *p1;
    float4 o = { (a.x+b.x)*linv, (a.y+b.y)*linv, (a.z+b.z)*linv, (a.w+b.w)*linv };
    *((float4*)(out + r*D_) + c4) = o;
}

// ---------------- fallback (round-2 style, no workspace) ----------------
#define FBQ 64
#define FBK 64
#define LDK 72
__global__ __launch_bounds__(256, 4) void fattn_fb(
    const float* __restrict__ q, const float* __restrict__ k,
    const float* __restrict__ v, float* __restrict__ out)
{
    __shared__ unsigned short Ks [FBK][LDK];
    __shared__ unsigned short Vts[D_][LDK];
    __shared__ unsigned short Ps [FBQ][LDK];
    const int tid  = threadIdx.x;
    const int wave = tid >> 6;
    const int m16  = tid & 15;
    const int quad = (tid & 63) >> 4;
    const int h    = blockIdx.y;
    const int b    = blockIdx.z;
    const int q0   = blockIdx.x * FBQ;
    const int bS   = b * S_;
    const int wq   = wave * 16;
    bf16x8 bq[2];
    {
        const int qrow = q0 + wq + m16;
        const float* qb = q + ((size_t)(bS + qrow)*H_ + h)*D_;
        #pragma unroll
        for (int kh = 0; kh < 2; ++kh) {
            const float4* qp = (const float4*)(qb + kh*32 + quad*8);
            bq[kh] = pack8s(qp[0], qp[1], QSCALE);
        }
    }
    const short ONE = 0x3F80;
    bf16x8 ones = { ONE,ONE,ONE,ONE,ONE,ONE,ONE,ONE };
    f32x4 oacc[4];
    f32x4 lacc = (f32x4){0.f,0.f,0.f,0.f};
    #pragma unroll
    for (int dt = 0; dt < 4; ++dt) oacc[dt] = (f32x4){0.f,0.f,0.f,0.f};
    const int vd  = tid & 63;
    const int vkg = tid >> 6;
    for (int kt = 0; kt < S_/FBK; ++kt) {
        const int k0 = kt * FBK;
        __syncthreads();
        #pragma unroll
        for (int i = 0; i < 2; ++i) {
            int chunk = tid + i*256;
            int row = chunk >> 3, c8 = chunk & 7;
            const float4* gp = (const float4*)(k + ((size_t)(bS + k0 + row)*H_ + h)*D_ + c8*8);
            *(bf16x8*)&Ks[row][c8*8] = pack8(gp[0], gp[1]);
        }
        {
            const float* vb = v + ((size_t)(bS + k0 + vkg*16)*H_ + h)*D_ + vd;
            bf16x8 t0, t1;
            #pragma unroll
            for (int i = 0; i < 8; ++i) t0[i] = f2bf(vb[(size_t)i * (H_*D_)]);
            #pragma unroll
            for (int i = 0; i < 8; ++i) t1[i] = f2bf(vb[(size_t)(i+8) * (H_*D_)]);
            *(bf16x8*)&Vts[vd][vkg*16]     = t0;
            *(bf16x8*)&Vts[vd][vkg*16 + 8] = t1;
        }
        __syncthreads();
        f32x4 sacc[4];
        #pragma unroll
        for (int mt = 0; mt < 4; ++mt) sacc[mt] = (f32x4){0.f,0.f,0.f,0.f};
        #pragma unroll
        for (int kh = 0; kh < 2; ++kh)
            #pragma unroll
            for (int mt = 0; mt < 4; ++mt) {
                bf16x8 aK = *(const bf16x8*)&Ks[mt*16 + m16][kh*32 + quad*8];
                sacc[mt] = __builtin_amdgcn_mfma_f32_16x16x32_bf16(aK, bq[kh], sacc[mt], 0,0,0);
            }
        #pragma unroll
        for (int mt = 0; mt < 4; ++mt) {
            bf16x4 pk;
            #pragma unroll
            for (int r = 0; r < 4; ++r)
                pk[r] = f2bf(__builtin_exp2f(sacc[mt][r]));
            *(bf16x4*)&Ps[wq + m16][mt*16 + quad*4] = pk;
        }
        #pragma unroll
        for (int kh = 0; kh < 2; ++kh) {
            bf16x8 bp = *(const bf16x8*)&Ps[wq + m16][kh*32 + quad*8];
            lacc = __builtin_amdgcn_mfma_f32_16x16x32_bf16(ones, bp, lacc, 0,0,0);
            #pragma unroll
            for (int dt = 0; dt < 4; ++dt) {
                bf16x8 aV = *(const bf16x8*)&Vts[dt*16 + m16][kh*32 + quad*8];
                oacc[dt] = __builtin_amdgcn_mfma_f32_16x16x32_bf16(aV, bp, oacc[dt], 0,0,0);
            }
        }
    }
    const float linv = 1.0f / lacc[0];
    const int orow = q0 + wq + m16;
    float* ob = out + ((size_t)(bS + orow)*H_ + h)*D_;
    #pragma unroll
    for (int dt = 0; dt < 4; ++dt) {
        float4 o4 = { oacc[dt][0]*linv, oacc[dt][1]*linv,
                      oacc[dt][2]*linv, oacc[dt][3]*linv };
        *(float4*)(ob + dt*16 + quad*4) = o4;
    }
}

extern "C" void kernel_launch(void* const* d_in, const int* in_sizes, int n_in,
                              void* d_out, int out_size, void* d_ws, size_t ws_size,
                              hipStream_t stream) {
    const float* q = (const float*)d_in[0];
    const float* k = (const float*)d_in[1];
    const float* v = (const float*)d_in[2];
    float* out = (float*)d_out;
    const size_t elems = (size_t)B_*H_*S_*D_;                 // 4.19M
    const size_t NR    = (size_t)B_*S_*H_;                    // 65536
    const size_t need_cast  = 2 * elems * sizeof(unsigned short);
    const size_t need_split = need_cast + 2*elems*sizeof(float) + 2*NR*sizeof(float);

    if (ws_size >= need_split) {
        unsigned short* kb  = (unsigned short*)d_ws;
        unsigned short* vtb = kb + elems;
        float* Op = (float*)(vtb + elems);
        float* lw = Op + 2*elems;
        cast_kv_kernel<<<dim3(S_/64, H_, B_*2), dim3(256), 0, stream>>>(k, v, kb, vtb);
        fattn_kernel<true><<<dim3(S_/BQ, H_, B_*2), dim3(256), 0, stream>>>(
            q, kb, vtb, out, Op, lw);
        combine_kernel<<<dim3((int)(NR/16)), dim3(256), 0, stream>>>(Op, lw, out);
    } else if (ws_size >= need_cast) {
        unsigned short* kb  = (unsigned short*)d_ws;
        unsigned short* vtb = kb + elems;
        cast_kv_kernel<<<dim3(S_/64, H_, B_*2), dim3(256), 0, stream>>>(k, v, kb, vtb);
        fattn_kernel<false><<<dim3(S_/BQ, H_, B_), dim3(256), 0, stream>>>(
            q, kb, vtb, out, nullptr, nullptr);
    } else {
        fattn_fb<<<dim3(S_/FBQ, H_, B_), dim3(256), 0, stream>>>(q, k, v, out);
    }
}

// Round 7
// 195.171 us; speedup vs baseline: 1.8550x; 1.0556x over previous
//
#include <hip/hip_runtime.h>
#include <hip/hip_bf16.h>

#define B_ 2
#define S_ 4096
#define H_ 8
#define D_ 64
#define BQ 128     // q-rows per WG (4 waves x 32 rows, 2 n-tiles per wave)
#define BK 64

#define GLOBAL_AS __attribute__((address_space(1)))
#define LDS_AS    __attribute__((address_space(3)))

typedef short bf16x8 __attribute__((ext_vector_type(8)));
typedef short bf16x4 __attribute__((ext_vector_type(4)));
typedef float f32x4  __attribute__((ext_vector_type(4)));

// log2(e)/8: folded into Q so the exp path is a bare v_exp_f32
#define QSCALE 0.18033688011112043f

__device__ __forceinline__ short f2bf(float f) {
    __bf16 h = (__bf16)f;                 // RTNE
    return __builtin_bit_cast(short, h);
}

__device__ __forceinline__ bf16x8 pack8(float4 f0, float4 f1) {
    bf16x8 r;
    r[0]=f2bf(f0.x); r[1]=f2bf(f0.y); r[2]=f2bf(f0.z); r[3]=f2bf(f0.w);
    r[4]=f2bf(f1.x); r[5]=f2bf(f1.y); r[6]=f2bf(f1.z); r[7]=f2bf(f1.w);
    return r;
}

__device__ __forceinline__ bf16x8 pack8s(float4 f0, float4 f1, float s) {
    bf16x8 r;
    r[0]=f2bf(f0.x*s); r[1]=f2bf(f0.y*s); r[2]=f2bf(f0.z*s); r[3]=f2bf(f0.w*s);
    r[4]=f2bf(f1.x*s); r[5]=f2bf(f1.y*s); r[6]=f2bf(f1.z*s); r[7]=f2bf(f1.w*s);
    return r;
}

// ---- fused pre-pass: role 0 = K fp32 [B,S,H,D] -> bf16 [B,H,S,D]
//                      role 1 = V fp32 [B,S,H,D] -> bf16 transposed [B,H,D,S]
__global__ __launch_bounds__(256) void cast_kv_kernel(
    const float* __restrict__ kin, const float* __restrict__ vin,
    unsigned short* __restrict__ kb, unsigned short* __restrict__ vtb)
{
    __shared__ float Lf[64][72];
    const int role = blockIdx.z & 1;
    const int b    = blockIdx.z >> 1;
    const int h    = blockIdx.y;
    const int s0   = blockIdx.x * 64;
    const int t    = threadIdx.x;

    if (role == 0) {
        int r = t >> 2, fq = t & 3;
        const float4* gp = (const float4*)(kin + (((size_t)(b*S_ + s0 + r)*H_ + h)*D_ + fq*16));
        bf16x8 o0 = pack8(gp[0], gp[1]);
        bf16x8 o1 = pack8(gp[2], gp[3]);
        unsigned short* ob = kb + ((size_t)(b*H_ + h)*S_ + s0 + r)*D_ + fq*16;
        *(bf16x8*)ob       = o0;
        *(bf16x8*)(ob + 8) = o1;
    } else {
        {
            int r  = t >> 2, fq = t & 3;
            const float4* gp = (const float4*)(vin + (((size_t)(b*S_ + s0 + r)*H_ + h)*D_ + fq*16));
            #pragma unroll
            for (int j = 0; j < 4; ++j)
                *(f32x4*)&Lf[r][fq*16 + 4*j] = (f32x4){gp[j].x, gp[j].y, gp[j].z, gp[j].w};
        }
        __syncthreads();
        {
            int d = t >> 2, sq = t & 3;
            bf16x8 o0, o1;
            #pragma unroll
            for (int j = 0; j < 8; ++j) o0[j] = f2bf(Lf[sq*16 + j][d]);
            #pragma unroll
            for (int j = 0; j < 8; ++j) o1[j] = f2bf(Lf[sq*16 + 8 + j][d]);
            unsigned short* ob = vtb + (((size_t)(b*H_ + h)*D_ + d)*S_ + s0 + sq*16);
            *(bf16x8*)(ob)     = o0;
            *(bf16x8*)(ob + 8) = o1;
        }
    }
}

// ---------------- main flash-attention kernel ----------------
// R11 = R0 (session-best verified base: 118us fattn / 196.7us total) + T1
// XCD-aware bijective block swizzle, nothing else. R0-R10 ledger: every
// scheduling change (dbuf/vmcnt/barriers/occupancy/BK) lands within +-4%
// of ~130us -> binder is shared; the one bad counter is FETCH 73.8MB vs
// 33.6MB logical (K/V refetched 3.4x: slab-sharing WGs round-robin across
// XCDs). Swizzle nl=(lin%8)*(nwg/8)+lin/8 groups each XCD's 128 slots as
// 4 full (b,h,half) slabs x 32 q-blocks; per-XCD set = 2MB < 4MB L2.
// nwg=1024/512, %8==0 -> bijective (ERRATA #11). Placement-independent
// correctness; worst case = no perf change.
// SPLIT: 2-way K-split, partial O^T + l to ws, combine kernel finishes.
// Q pre-scaled by log2e/8 -> P = exp2(S) bare. bf16 K [B,H,S,D] / V^T
// [B,H,D,S] staged via global_load_lds w16 with chunk-XOR swizzle.
template<bool SPLIT>
__global__ __launch_bounds__(256, 4) void fattn_kernel(
    const float* __restrict__ q, const unsigned short* __restrict__ kb,
    const unsigned short* __restrict__ vtb, float* __restrict__ out,
    float* __restrict__ Op, float* __restrict__ lw)
{
    __shared__ unsigned short Ks [BK][64];
    __shared__ unsigned short Vts[D_][64];
    __shared__ unsigned short Ps [BQ][64];

    const int tid  = threadIdx.x;
    const int wave = tid >> 6;
    const int lane = tid & 63;
    const int m16  = tid & 15;
    const int quad = (tid & 63) >> 4;

    // ---- T1 XCD swizzle: lin = x + 32*y + 256*z (x fastest); remap so each
    // XCD (lin%8 placement heuristic) owns 4 contiguous slabs of 32 q-blocks.
    const int lin  = blockIdx.x + 32*blockIdx.y + 256*blockIdx.z;
    const int nl   = (lin & 7)*(SPLIT ? 128 : 64) + (lin >> 3);
    const int xq   = nl & 31;            // q-block
    const int h    = (nl >> 5) & 7;      // head
    const int bz   = nl >> 8;            // slab z
    const int b    = SPLIT ? (bz >> 1) : bz;
    const int half = SPLIT ? (bz & 1)  : 0;
    const int kt0  = half * 32;
    const int nkt  = SPLIT ? 32 : 64;
    const int q0   = xq * BQ;
    const int bS   = b * S_;
    const int wq2  = wave * 32;          // this wave's 32 q-rows
    const int r7   = m16 & 7;

    // ---- per-lane LDS element offsets (tile-invariant, swizzled)
    // aK/aV A-frag: row = t16*16 + m16, chunk = (kh*4+quad)^r7
    int ksoff[2][4];
    #pragma unroll
    for (int kh = 0; kh < 2; ++kh)
        #pragma unroll
        for (int t4 = 0; t4 < 4; ++t4)
            ksoff[kh][t4] = (t4*16 + m16)*64 + (((kh*4 + quad) ^ r7)*8);
    // P^T B-frag read: row = wq2 + n*16 + m16
    int proff[2][2];
    #pragma unroll
    for (int n = 0; n < 2; ++n)
        #pragma unroll
        for (int kh = 0; kh < 2; ++kh)
            proff[n][kh] = (wq2 + n*16 + m16)*64 + (((kh*4 + quad) ^ r7)*8);
    // P write: lane holds keys mt*16+quad*4..+3 at qrow m16 (per n)
    int pwoff[2][4];
    #pragma unroll
    for (int n = 0; n < 2; ++n)
        #pragma unroll
        for (int mt = 0; mt < 4; ++mt)
            pwoff[n][mt] = (wq2 + n*16 + m16)*64
                         + (((2*mt + (quad>>1)) ^ r7)*8) + (quad&1)*4;

    // ---- staging lane mapping (slot = lane): 256 threads cover 64 rows x 64d
    const int srow = (lane >> 3);
    const int c8g  = (lane & 7) ^ srow;
    const int wqs  = wave * 16;                 // staging row base (NOT wq2)
    const unsigned short* ksg[2];
    const unsigned short* vtg[2];
    #pragma unroll
    for (int it = 0; it < 2; ++it) {
        int rk = wqs + it*8 + srow;
        ksg[it] = kb  + ((size_t)(b*H_ + h)*S_ + rk)*64 + c8g*8;
        vtg[it] = vtb + ((size_t)(b*H_ + h)*D_ + rk)*(size_t)S_ + c8g*8;
    }

    // ---- Q as B-fragments of Q^T, pre-scaled; 2 n-tiles
    bf16x8 bq[2][2];
    #pragma unroll
    for (int n = 0; n < 2; ++n) {
        const int qrow = q0 + wq2 + n*16 + m16;
        const float* qp = q + ((size_t)(bS + qrow)*H_ + h)*D_;
        #pragma unroll
        for (int kh = 0; kh < 2; ++kh) {
            const float4* q4 = (const float4*)(qp + kh*32 + quad*8);
            bq[n][kh] = pack8s(q4[0], q4[1], QSCALE);
        }
    }

    const short ONE = 0x3F80;
    bf16x8 ones = { ONE,ONE,ONE,ONE,ONE,ONE,ONE,ONE };

    f32x4 oacc[2][4];
    f32x4 lacc[2];
    #pragma unroll
    for (int n = 0; n < 2; ++n) {
        lacc[n] = (f32x4){0.f,0.f,0.f,0.f};
        #pragma unroll
        for (int dt = 0; dt < 4; ++dt) oacc[n][dt] = (f32x4){0.f,0.f,0.f,0.f};
    }

    for (int i = 0; i < nkt; ++i) {
        const int kt = kt0 + i;
        __syncthreads();

        #pragma unroll
        for (int it = 0; it < 2; ++it) {
            __builtin_amdgcn_global_load_lds(
                (const GLOBAL_AS void*)(ksg[it] + (size_t)kt*BK*64),
                (LDS_AS void*)&Ks[wqs + it*8][0], 16, 0, 0);
            __builtin_amdgcn_global_load_lds(
                (const GLOBAL_AS void*)(vtg[it] + (size_t)kt*BK),
                (LDS_AS void*)&Vts[wqs + it*8][0], 16, 0, 0);
        }
        __syncthreads();

        // ---- S^T = K Q^T, then P = exp2(S^T) -> Ps, per mt (short sacc live range)
        #pragma unroll
        for (int mt = 0; mt < 4; ++mt) {
            f32x4 s0 = (f32x4){0.f,0.f,0.f,0.f};
            f32x4 s1 = (f32x4){0.f,0.f,0.f,0.f};
            #pragma unroll
            for (int kh = 0; kh < 2; ++kh) {
                bf16x8 aK = *(const bf16x8*)&Ks[0][ksoff[kh][mt]];
                s0 = __builtin_amdgcn_mfma_f32_16x16x32_bf16(aK, bq[0][kh], s0, 0,0,0);
                s1 = __builtin_amdgcn_mfma_f32_16x16x32_bf16(aK, bq[1][kh], s1, 0,0,0);
            }
            bf16x4 p0, p1;
            #pragma unroll
            for (int r = 0; r < 4; ++r) {
                p0[r] = f2bf(__builtin_exp2f(s0[r]));
                p1[r] = f2bf(__builtin_exp2f(s1[r]));
            }
            *(bf16x4*)&Ps[0][pwoff[0][mt]] = p0;
            *(bf16x4*)&Ps[0][pwoff[1][mt]] = p1;
        }

        // ---- O^T += V^T P^T ; l += ones * P^T   (wave-private Ps rows)
        #pragma unroll
        for (int kh = 0; kh < 2; ++kh) {
            bf16x8 bp0 = *(const bf16x8*)&Ps[0][proff[0][kh]];
            bf16x8 bp1 = *(const bf16x8*)&Ps[0][proff[1][kh]];
            lacc[0] = __builtin_amdgcn_mfma_f32_16x16x32_bf16(ones, bp0, lacc[0], 0,0,0);
            lacc[1] = __builtin_amdgcn_mfma_f32_16x16x32_bf16(ones, bp1, lacc[1], 0,0,0);
            #pragma unroll
            for (int dt = 0; dt < 4; ++dt) {
                bf16x8 aV = *(const bf16x8*)&Vts[0][ksoff[kh][dt]];
                oacc[0][dt] = __builtin_amdgcn_mfma_f32_16x16x32_bf16(aV, bp0, oacc[0][dt], 0,0,0);
                oacc[1][dt] = __builtin_amdgcn_mfma_f32_16x16x32_bf16(aV, bp1, oacc[1][dt], 0,0,0);
            }
        }
    }

    #pragma unroll
    for (int n = 0; n < 2; ++n) {
        const int orow = q0 + wq2 + n*16 + m16;
        if constexpr (SPLIT) {
            float* ob = Op + (size_t)half*((size_t)B_*S_*H_*D_)
                           + ((size_t)(bS + orow)*H_ + h)*D_;
            #pragma unroll
            for (int dt = 0; dt < 4; ++dt) {
                float4 o4 = { oacc[n][dt][0], oacc[n][dt][1],
                              oacc[n][dt][2], oacc[n][dt][3] };
                *(float4*)(ob + dt*16 + quad*4) = o4;
            }
            if (quad == 0)
                lw[(size_t)half*((size_t)B_*S_*H_) + (size_t)(bS + orow)*H_ + h] = lacc[n][0];
        } else {
            const float linv = 1.0f / lacc[n][0];
            float* ob = out + ((size_t)(bS + orow)*H_ + h)*D_;
            #pragma unroll
            for (int dt = 0; dt < 4; ++dt) {
                float4 o4 = { oacc[n][dt][0]*linv, oacc[n][dt][1]*linv,
                              oacc[n][dt][2]*linv, oacc[n][dt][3]*linv };
                *(float4*)(ob + dt*16 + quad*4) = o4;
            }
        }
    }
}

// ---- combine: out = (O0 + O1) / (l0 + l1)
__global__ __launch_bounds__(256) void combine_kernel(
    const float* __restrict__ Op, const float* __restrict__ lw,
    float* __restrict__ out)
{
    const size_t NR = (size_t)B_*S_*H_;
    const size_t NO = NR * D_;
    const int t = threadIdx.x;
    size_t r  = (size_t)blockIdx.x * 16 + (t >> 4);
    int   c4  = t & 15;
    const float4* p0 = (const float4*)(Op + r*D_) + c4;
    const float4* p1 = (const float4*)(Op + NO + r*D_) + c4;
    float linv = 1.0f / (lw[r] + lw[NR + r]);
    float4 a = *p0, b = *p1;
    float4 o = { (a.x+b.x)*linv, (a.y+b.y)*linv, (a.z+b.z)*linv, (a.w+b.w)*linv };
    *((float4*)(out + r*D_) + c4) = o;
}

// ---------------- fallback (round-2 style, no workspace) ----------------
#define FBQ 64
#define LDK 72
__global__ __launch_bounds__(256, 4) void fattn_fb(
    const float* __restrict__ q, const float* __restrict__ k,
    const float* __restrict__ v, float* __restrict__ out)
{
    __shared__ unsigned short Ks [BK][LDK];
    __shared__ unsigned short Vts[D_][LDK];
    __shared__ unsigned short Ps [FBQ][LDK];
    const int tid  = threadIdx.x;
    const int wave = tid >> 6;
    const int m16  = tid & 15;
    const int quad = (tid & 63) >> 4;
    const int h    = blockIdx.y;
    const int b    = blockIdx.z;
    const int q0   = blockIdx.x * FBQ;
    const int bS   = b * S_;
    const int wq   = wave * 16;
    bf16x8 bq[2];
    {
        const int qrow = q0 + wq + m16;
        const float* qb = q + ((size_t)(bS + qrow)*H_ + h)*D_;
        #pragma unroll
        for (int kh = 0; kh < 2; ++kh) {
            const float4* qp = (const float4*)(qb + kh*32 + quad*8);
            bq[kh] = pack8s(qp[0], qp[1], QSCALE);
        }
    }
    const short ONE = 0x3F80;
    bf16x8 ones = { ONE,ONE,ONE,ONE,ONE,ONE,ONE,ONE };
    f32x4 oacc[4];
    f32x4 lacc = (f32x4){0.f,0.f,0.f,0.f};
    #pragma unroll
    for (int dt = 0; dt < 4; ++dt) oacc[dt] = (f32x4){0.f,0.f,0.f,0.f};
    const int vd  = tid & 63;
    const int vkg = tid >> 6;
    for (int kt = 0; kt < S_/BK; ++kt) {
        const int k0 = kt * BK;
        __syncthreads();
        #pragma unroll
        for (int i = 0; i < 2; ++i) {
            int chunk = tid + i*256;
            int row = chunk >> 3, c8 = chunk & 7;
            const float4* gp = (const float4*)(k + ((size_t)(bS + k0 + row)*H_ + h)*D_ + c8*8);
            *(bf16x8*)&Ks[row][c8*8] = pack8(gp[0], gp[1]);
        }
        {
            const float* vb = v + ((size_t)(bS + k0 + vkg*16)*H_ + h)*D_ + vd;
            bf16x8 t0, t1;
            #pragma unroll
            for (int i = 0; i < 8; ++i) t0[i] = f2bf(vb[(size_t)i * (H_*D_)]);
            #pragma unroll
            for (int i = 0; i < 8; ++i) t1[i] = f2bf(vb[(size_t)(i+8) * (H_*D_)]);
            *(bf16x8*)&Vts[vd][vkg*16]     = t0;
            *(bf16x8*)&Vts[vd][vkg*16 + 8] = t1;
        }
        __syncthreads();
        f32x4 sacc[4];
        #pragma unroll
        for (int mt = 0; mt < 4; ++mt) sacc[mt] = (f32x4){0.f,0.f,0.f,0.f};
        #pragma unroll
        for (int kh = 0; kh < 2; ++kh)
            #pragma unroll
            for (int mt = 0; mt < 4; ++mt) {
                bf16x8 aK = *(const bf16x8*)&Ks[mt*16 + m16][kh*32 + quad*8];
                sacc[mt] = __builtin_amdgcn_mfma_f32_16x16x32_bf16(aK, bq[kh], sacc[mt], 0,0,0);
            }
        #pragma unroll
        for (int mt = 0; mt < 4; ++mt) {
            bf16x4 pk;
            #pragma unroll
            for (int r = 0; r < 4; ++r)
                pk[r] = f2bf(__builtin_exp2f(sacc[mt][r]));
            *(bf16x4*)&Ps[wq + m16][mt*16 + quad*4] = pk;
        }
        #pragma unroll
        for (int kh = 0; kh < 2; ++kh) {
            bf16x8 bp = *(const bf16x8*)&Ps[wq + m16][kh*32 + quad*8];
            lacc = __builtin_amdgcn_mfma_f32_16x16x32_bf16(ones, bp, lacc, 0,0,0);
            #pragma unroll
            for (int dt = 0; dt < 4; ++dt) {
                bf16x8 aV = *(const bf16x8*)&Vts[dt*16 + m16][kh*32 + quad*8];
                oacc[dt] = __builtin_amdgcn_mfma_f32_16x16x32_bf16(aV, bp, oacc[dt], 0,0,0);
            }
        }
    }
    const float linv = 1.0f / lacc[0];
    const int orow = q0 + wq + m16;
    float* ob = out + ((size_t)(bS + orow)*H_ + h)*D_;
    #pragma unroll
    for (int dt = 0; dt < 4; ++dt) {
        float4 o4 = { oacc[dt][0]*linv, oacc[dt][1]*linv,
                      oacc[dt][2]*linv, oacc[dt][3]*linv };
        *(float4*)(ob + dt*16 + quad*4) = o4;
    }
}

extern "C" void kernel_launch(void* const* d_in, const int* in_sizes, int n_in,
                              void* d_out, int out_size, void* d_ws, size_t ws_size,
                              hipStream_t stream) {
    const float* q = (const float*)d_in[0];
    const float* k = (const float*)d_in[1];
    const float* v = (const float*)d_in[2];
    float* out = (float*)d_out;
    const size_t elems = (size_t)B_*H_*S_*D_;                 // 4.19M
    const size_t NR    = (size_t)B_*S_*H_;                    // 65536
    const size_t need_cast  = 2 * elems * sizeof(unsigned short);
    const size_t need_split = need_cast + 2*elems*sizeof(float) + 2*NR*sizeof(float);

    if (ws_size >= need_split) {
        unsigned short* kb  = (unsigned short*)d_ws;
        unsigned short* vtb = kb + elems;
        float* Op = (float*)(vtb + elems);
        float* lw = Op + 2*elems;
        cast_kv_kernel<<<dim3(S_/64, H_, B_*2), dim3(256), 0, stream>>>(k, v, kb, vtb);
        fattn_kernel<true><<<dim3(S_/BQ, H_, B_*2), dim3(256), 0, stream>>>(
            q, kb, vtb, out, Op, lw);
        combine_kernel<<<dim3((int)(NR/16)), dim3(256), 0, stream>>>(Op, lw, out);
    } else if (ws_size >= need_cast) {
        unsigned short* kb  = (unsigned short*)d_ws;
        unsigned short* vtb = kb + elems;
        cast_kv_kernel<<<dim3(S_/64, H_, B_*2), dim3(256), 0, stream>>>(k, v, kb, vtb);
        fattn_kernel<false><<<dim3(S_/BQ, H_, B_), dim3(256), 0, stream>>>(
            q, kb, vtb, out, nullptr, nullptr);
    } else {
        fattn_fb<<<dim3(S_/FBQ, H_, B_), dim3(256), 0, stream>>>(q, k, v, out);
    }
}